// Round 5
// baseline (1996.728 us; speedup 1.0000x reference)
//
#include <hip/hip_runtime.h>

#define T 4096
#define EP 8                      // steps per barrier epoch
#define RING 32                   // LDS ring depth (disjoint writer/reader mod 32)
#define NEP (T / EP + 2)          // 514 epochs: pipeline depth 2 epochs

// tanh(x) = 1 - 2/(exp(2x)+1). Branch-free, ~1e-6 err; exonerated vs exact
// (identical absmax over 4096 recurrent steps).
__device__ __forceinline__ float fast_tanh(float x) {
    float e = __expf(2.0f * x);
    float r = __builtin_amdgcn_rcpf(e + 1.0f);
    return fmaf(-2.0f, r, 1.0f);
}

// v_readlane broadcast (SGPR result usable as the scalar FMA operand).
__device__ __forceinline__ float lane_bcast(float v, int j) {
    return __uint_as_float(__builtin_amdgcn_readlane(__float_as_uint(v), j));
}

// 16/64-scalar residency anchors (once per epoch; near-zero cost).
#define ANCHOR16(a, b) asm volatile("" : \
    "+v"((a)[(b)+0]),  "+v"((a)[(b)+1]),  "+v"((a)[(b)+2]),  "+v"((a)[(b)+3]),  \
    "+v"((a)[(b)+4]),  "+v"((a)[(b)+5]),  "+v"((a)[(b)+6]),  "+v"((a)[(b)+7]),  \
    "+v"((a)[(b)+8]),  "+v"((a)[(b)+9]),  "+v"((a)[(b)+10]), "+v"((a)[(b)+11]), \
    "+v"((a)[(b)+12]), "+v"((a)[(b)+13]), "+v"((a)[(b)+14]), "+v"((a)[(b)+15]))
#define ANCHOR64(a) do { ANCHOR16(a, 0); ANCHOR16(a, 16); \
                         ANCHOR16(a, 32); ANCHOR16(a, 48); } while (0)

// One recurrence step: returns tanh(init + W@h_prev) for this lane's output
// row. Accumulation sets/order identical to R1/R2 (acc[u&3], u ascending)
// -> bit-identical numerics. w is a register array (compile-time indices).
__device__ __forceinline__ float rnn_step(const float (&w)[64], float init, float hp) {
    float a0 = init, a1 = 0.f, a2 = 0.f, a3 = 0.f;
#pragma unroll
    for (int jb = 0; jb < 64; jb += 8) {
        float h0 = lane_bcast(hp, jb + 0);
        float h1 = lane_bcast(hp, jb + 1);
        float h2 = lane_bcast(hp, jb + 2);
        float h3 = lane_bcast(hp, jb + 3);
        float h4 = lane_bcast(hp, jb + 4);
        float h5 = lane_bcast(hp, jb + 5);
        float h6 = lane_bcast(hp, jb + 6);
        float h7 = lane_bcast(hp, jb + 7);
        a0 = fmaf(w[jb + 0], h0, a0);
        a1 = fmaf(w[jb + 1], h1, a1);
        a2 = fmaf(w[jb + 2], h2, a2);
        a3 = fmaf(w[jb + 3], h3, a3);
        a0 = fmaf(w[jb + 4], h4, a0);
        a1 = fmaf(w[jb + 5], h5, a1);
        a2 = fmaf(w[jb + 6], h6, a2);
        a3 = fmaf(w[jb + 7], h7, a3);
    }
    return fast_tanh((a0 + a1) + (a2 + a3));
}

// ---------------------------------------------------------------------------
// prep: pre[s][t][i] = b_ih0[i] + b_hh0[i] + sum_d W_ih0[i][d] * in[0,t,d]
// Only batch element 0 of x / y matters (reference uses e[0], o[0] only).
// ---------------------------------------------------------------------------
__global__ void prep_kernel(const float* __restrict__ x, const float* __restrict__ y,
                            const float* __restrict__ eW, const float* __restrict__ ebi,
                            const float* __restrict__ ebh,
                            const float* __restrict__ oW, const float* __restrict__ obi,
                            const float* __restrict__ obh,
                            float* __restrict__ pre)
{
    int idx = blockIdx.x * blockDim.x + threadIdx.x;   // 2*T*64 threads
    int i = idx & 63;
    int t = (idx >> 6) & (T - 1);
    int s = idx >> 18;
    const float* in = s ? y : x;          // batch 0 = first T*3 floats
    const float* W  = s ? oW : eW;        // [64][3]
    const float* bi = s ? obi : ebi;
    const float* bh = s ? obh : ebh;
    float v = bi[i] + bh[i]
            + W[i*3+0]*in[t*3+0] + W[i*3+1]*in[t*3+1] + W[i*3+2]*in[t*3+2];
    pre[idx] = v;
}

// ---------------------------------------------------------------------------
// seq: grid=2 (one block per RNN), 4 specialized waves, barrier per EP epoch.
// R4 post-mortem: LDS broadcast put a ds roundtrip in the serial chain
// (+225 cyc/step) -> reverted to readlane. R3 showed the recurrence wave is
// issue-bound at ~2.3 cyc/inst with ~2x the source-level instruction count;
// VGPR_Count 48-68 (< the 64 weights) + zero scratch traffic => the weight
// arrays were parked in AGPRs by the allocator (unrolled epoch body pressure)
// and every use paid a hidden accvgpr move. R5: ROLL the 8-step loop
// (#pragma unroll 1), depth-3 rotating p-prefetch instead of 16 p-registers
// -> live set ~85 regs -> weights stay in arch VGPRs.
//   wave0 @ epoch k: h0[t] = tanh(p[t] + Whh0@h0[t-1]), t in [8k, 8k+8)
//   wave1/wave2 @ epoch k: q[t] = b1 + Wih1@h0[t], t-split halves of [8k-8,8k)
//   wave3 @ epoch k: h1[t] = tanh(q[t] + Whh1@h1[t-1]), t in [8k-16, 8k-8)
// Ring safety (mod 32): cross-wave readers are >=1 barrier behind writers;
// wave3's in-epoch q prefetch only touches [base, base+EP) (all published
// before this epoch's opening barrier).
// ---------------------------------------------------------------------------
__global__ __launch_bounds__(256, 1) void seq_kernel(
    const float* __restrict__ pre,            // [2][T][64]
    const float* __restrict__ eWhh0, const float* __restrict__ eWih1,
    const float* __restrict__ eWhh1, const float* __restrict__ ebih1,
    const float* __restrict__ ebhh1,
    const float* __restrict__ oWhh0, const float* __restrict__ oWih1,
    const float* __restrict__ oWhh1, const float* __restrict__ obih1,
    const float* __restrict__ obhh1,
    float* __restrict__ hlast)                // [2][64]
{
    const int s    = blockIdx.x;
    const int wv   = threadIdx.x >> 6;
    const int lane = threadIdx.x & 63;

    __shared__ __align__(16) float h0ring[RING][64];
    __shared__ __align__(16) float qring[RING][64];

    const float* p = pre + s * T * 64;

    if (wv == 0) {
        // ---------- layer-0 recurrence wave ----------
        const float* Whh0 = s ? oWhh0 : eWhh0;
        float w0[64];
#pragma unroll
        for (int j = 0; j < 64; ++j) w0[j] = Whh0[lane * 64 + j];

        float hp = 0.f;                        // h0[t-1]
        // depth-3 rotating p prefetch: q1=p[t], q2=p[t+1], q3=p[t+2]
        float q1 = p[0 * 64 + lane];
        float q2 = p[1 * 64 + lane];
        float q3 = p[2 * 64 + lane];

        for (int k = 0; k < NEP; ++k) {
            ANCHOR64(w0);                      // weights stay in arch VGPRs
            const int base = k * EP;
            if (base < T) {                    // wave-uniform scalar branch
#pragma unroll 1
                for (int i = 0; i < EP; ++i) {
                    const int t  = base + i;
                    const float pc = q1;
                    q1 = q2; q2 = q3;
                    const int tl = (t + 3 < T) ? (t + 3) : (T - 1);  // clamp
                    q3 = p[tl * 64 + lane];    // consumed 3 steps later
                    hp = rnn_step(w0, pc, hp);
                    h0ring[t & (RING - 1)][lane] = hp;   // publish
                }
            }
            __syncthreads();
        }
    } else if (wv <= 2) {
        // ---------- helper waves: layer-1 input projection, t-split ----------
        const float* Wih1 = s ? oWih1 : eWih1;
        const float  b1   = s ? (obih1[lane] + obhh1[lane])
                              : (ebih1[lane] + ebhh1[lane]);
        float wi[64];
#pragma unroll
        for (int j = 0; j < 64; ++j) wi[j] = Wih1[lane * 64 + j];

        const int i0 = (wv - 1) * (EP / 2);    // wave1: t 0..3, wave2: t 4..7

        for (int k = 0; k < NEP; ++k) {
            ANCHOR64(wi);
            const int base = k * EP - EP;
            if (base >= 0 && base < T) {
#pragma unroll
                for (int i = 0; i < EP / 2; ++i) {
                    const int t = base + i0 + i;
                    const float4* hv = (const float4*)h0ring[t & (RING - 1)];
                    float q[4] = { b1, 0.f, 0.f, 0.f };
#pragma unroll
                    for (int j4 = 0; j4 < 16; ++j4) {
                        float4 u = hv[j4];
                        q[0] = fmaf(wi[4*j4+0], u.x, q[0]);
                        q[1] = fmaf(wi[4*j4+1], u.y, q[1]);
                        q[2] = fmaf(wi[4*j4+2], u.z, q[2]);
                        q[3] = fmaf(wi[4*j4+3], u.w, q[3]);
                    }
                    qring[t & (RING - 1)][lane] = (q[0] + q[1]) + (q[2] + q[3]);
                }
            }
            __syncthreads();
        }
    } else {
        // ---------- layer-1 recurrence wave ----------
        const float* Whh1 = s ? oWhh1 : eWhh1;
        float w1[64];
#pragma unroll
        for (int j = 0; j < 64; ++j) w1[j] = Whh1[lane * 64 + j];

        float hp = 0.f;                        // h1[t-1]
        for (int k = 0; k < NEP; ++k) {
            ANCHOR64(w1);
            const int base = k * EP - 2 * EP;
            if (base >= 0) {                   // base+EP-1 <= T-1 by construction
                // depth-1 in-epoch q prefetch (all slots published >=1 barrier ago)
                float qn = qring[base & (RING - 1)][lane];
#pragma unroll 1
                for (int i = 0; i < EP; ++i) {
                    const float qc = qn;
                    const int ip = (i < EP - 1) ? (i + 1) : (EP - 1);   // clamp
                    qn = qring[(base + ip) & (RING - 1)][lane];
                    hp = rnn_step(w1, qc, hp);
                }
            }
            __syncthreads();
        }
        hlast[s * 64 + lane] = hp;             // h1[T-1]
    }
}

// ---------------------------------------------------------------------------
// head: e0 = fce_w@hx + fce_b ; o0 = fco_w@hy + fco_b ; zz=[e0,o0,z];
//       h = relu(fc1_w@zz + fc1_b) ; out = fc2_w@h + fc2_b
// ---------------------------------------------------------------------------
__global__ void head_kernel(const float* __restrict__ hlast,   // [2][64]
                            const float* __restrict__ z,
                            const float* __restrict__ fce_w, const float* __restrict__ fce_b,
                            const float* __restrict__ fco_w, const float* __restrict__ fco_b,
                            const float* __restrict__ fc1_w, const float* __restrict__ fc1_b,
                            const float* __restrict__ fc2_w, const float* __restrict__ fc2_b,
                            float* __restrict__ out)            // [5]
{
    const int lane = threadIdx.x;   // 64 threads
    __shared__ float zz[9];
    __shared__ float hh[64];

    if (lane < 2) {
        float sacc = fce_b[lane];
        for (int j = 0; j < 64; ++j) sacc += fce_w[lane * 64 + j] * hlast[j];
        zz[lane] = sacc;
    } else if (lane < 4) {
        int r = lane - 2;
        float sacc = fco_b[r];
        for (int j = 0; j < 64; ++j) sacc += fco_w[r * 64 + j] * hlast[64 + j];
        zz[lane] = sacc;
    } else if (lane < 9) {
        zz[lane] = z[lane - 4];
    }
    __syncthreads();

    float sacc = fc1_b[lane];
#pragma unroll
    for (int j = 0; j < 9; ++j) sacc += fc1_w[lane * 9 + j] * zz[j];
    hh[lane] = fmaxf(sacc, 0.f);
    __syncthreads();

    if (lane < 5) {
        float o = fc2_b[lane];
        for (int i = 0; i < 64; ++i) o += fc2_w[lane * 64 + i] * hh[i];
        out[lane] = o;
    }
}

// ---------------------------------------------------------------------------
extern "C" void kernel_launch(void* const* d_in, const int* in_sizes, int n_in,
                              void* d_out, int out_size, void* d_ws, size_t ws_size,
                              hipStream_t stream)
{
    const float* x      = (const float*)d_in[0];
    const float* y      = (const float*)d_in[1];
    const float* z      = (const float*)d_in[2];
    const float* e_Wih0 = (const float*)d_in[3];
    const float* e_Whh0 = (const float*)d_in[4];
    const float* e_bih0 = (const float*)d_in[5];
    const float* e_bhh0 = (const float*)d_in[6];
    const float* e_Wih1 = (const float*)d_in[7];
    const float* e_Whh1 = (const float*)d_in[8];
    const float* e_bih1 = (const float*)d_in[9];
    const float* e_bhh1 = (const float*)d_in[10];
    const float* o_Wih0 = (const float*)d_in[11];
    const float* o_Whh0 = (const float*)d_in[12];
    const float* o_bih0 = (const float*)d_in[13];
    const float* o_bhh0 = (const float*)d_in[14];
    const float* o_Wih1 = (const float*)d_in[15];
    const float* o_Whh1 = (const float*)d_in[16];
    const float* o_bih1 = (const float*)d_in[17];
    const float* o_bhh1 = (const float*)d_in[18];
    const float* fce_w  = (const float*)d_in[19];
    const float* fce_b  = (const float*)d_in[20];
    const float* fco_w  = (const float*)d_in[21];
    const float* fco_b  = (const float*)d_in[22];
    const float* fc1_w  = (const float*)d_in[23];
    const float* fc1_b  = (const float*)d_in[24];
    const float* fc2_w  = (const float*)d_in[25];
    const float* fc2_b  = (const float*)d_in[26];

    float* pre   = (float*)d_ws;            // 2*T*64 floats = 2 MB
    float* hlast = pre + 2 * T * 64;        // 128 floats
    float* out   = (float*)d_out;

    prep_kernel<<<(2 * T * 64) / 256, 256, 0, stream>>>(
        x, y, e_Wih0, e_bih0, e_bhh0, o_Wih0, o_bih0, o_bhh0, pre);

    seq_kernel<<<2, 256, 0, stream>>>(
        pre,
        e_Whh0, e_Wih1, e_Whh1, e_bih1, e_bhh1,
        o_Whh0, o_Wih1, o_Whh1, o_bih1, o_bhh1,
        hlast);

    head_kernel<<<1, 64, 0, stream>>>(
        hlast, z, fce_w, fce_b, fco_w, fco_b, fc1_w, fc1_b, fc2_w, fc2_b, out);
}

// Round 6
// 1513.105 us; speedup vs baseline: 1.3196x; 1.3196x over previous
//
#include <hip/hip_runtime.h>

#define T 4096
#define EP 8                      // steps per barrier epoch
#define RING 32                   // LDS ring depth (disjoint writer/reader mod 32)
#define NEP (T / EP + 2)          // 514 epochs: pipeline depth 2 epochs

// tanh(x) = 1 - 2/(exp(2x)+1). Branch-free, ~1e-6 err.
__device__ __forceinline__ float fast_tanh(float x) {
    float e = __expf(2.0f * x);
    float r = __builtin_amdgcn_rcpf(e + 1.0f);
    return fmaf(-2.0f, r, 1.0f);
}

// 16/64-scalar residency anchors (once per epoch; near-zero cost).
#define ANCHOR16(a, b) asm volatile("" : \
    "+v"((a)[(b)+0]),  "+v"((a)[(b)+1]),  "+v"((a)[(b)+2]),  "+v"((a)[(b)+3]),  \
    "+v"((a)[(b)+4]),  "+v"((a)[(b)+5]),  "+v"((a)[(b)+6]),  "+v"((a)[(b)+7]),  \
    "+v"((a)[(b)+8]),  "+v"((a)[(b)+9]),  "+v"((a)[(b)+10]), "+v"((a)[(b)+11]), \
    "+v"((a)[(b)+12]), "+v"((a)[(b)+13]), "+v"((a)[(b)+14]), "+v"((a)[(b)+15]))
#define ANCHOR64(a) do { ANCHOR16(a, 0); ANCHOR16(a, 16); \
                         ANCHOR16(a, 32); ANCHOR16(a, 48); } while (0)

// ---------------------------------------------------------------------------
// DPP rotation-decomposed matvec (R6):
//   sum_j W[i][j]*h[j] = sum_{k=0..3} sum_{r=0..15} wd[16k+r] * rot_r(h_k)[i]
// where h_k[i] = h[i ^ (k<<4)] (3 ds_bpermute XOR-copies + h itself) and
// rot_r = DPP row_ror:r (16-lane row rotation). Weights pre-permuted per lane
// so the product at lane i picks exactly W[i][j]. No readlane / SGPR operands
// / LDS latency in the serial chain. DPP direction (does row_ror:r deliver
// src[(i+r)&15] or src[(i-r)&15]?) is probed at runtime; the weight
// permutation adapts, so either hardware convention yields correct results.
// ---------------------------------------------------------------------------
#define ROTF(acc, v, w, R) \
    (acc) = fmaf(__int_as_float(__builtin_amdgcn_update_dpp( \
        0, __float_as_int(v), 0x120 + (R), 0xF, 0xF, false)), (w), (acc))

// One 16-rotation block: r=0 plain, r=1..15 DPP. acc index = r & 3.
#define KBLOCK(v, wd, B) do { \
    a0 = fmaf((v), (wd)[(B) + 0], a0); \
    ROTF(a1, (v), (wd)[(B) + 1],  1);  ROTF(a2, (v), (wd)[(B) + 2],  2); \
    ROTF(a3, (v), (wd)[(B) + 3],  3);  ROTF(a0, (v), (wd)[(B) + 4],  4); \
    ROTF(a1, (v), (wd)[(B) + 5],  5);  ROTF(a2, (v), (wd)[(B) + 6],  6); \
    ROTF(a3, (v), (wd)[(B) + 7],  7);  ROTF(a0, (v), (wd)[(B) + 8],  8); \
    ROTF(a1, (v), (wd)[(B) + 9],  9);  ROTF(a2, (v), (wd)[(B) +10], 10); \
    ROTF(a3, (v), (wd)[(B) +11], 11);  ROTF(a0, (v), (wd)[(B) +12], 12); \
    ROTF(a1, (v), (wd)[(B) +13], 13);  ROTF(a2, (v), (wd)[(B) +14], 14); \
    ROTF(a3, (v), (wd)[(B) +15], 15); \
} while (0)

// One recurrence step. k=0 block consumes hp directly while the 3 bpermutes
// (XOR-copies) are still in flight -> their latency hides under ~32 VALU ops.
__device__ __forceinline__ float rnn_step_dpp(const float (&wd)[64], float init, float hp,
                                              int a16, int a32, int a48) {
    const int hb = __float_as_int(hp);
    const int b1i = __builtin_amdgcn_ds_bpermute(a16, hb);   // h[i^16]
    const int b2i = __builtin_amdgcn_ds_bpermute(a32, hb);   // h[i^32]
    const int b3i = __builtin_amdgcn_ds_bpermute(a48, hb);   // h[i^48]
    float a0 = init, a1 = 0.f, a2 = 0.f, a3 = 0.f;
    KBLOCK(hp, wd, 0);
    const float v1 = __int_as_float(b1i); KBLOCK(v1, wd, 16);
    const float v2 = __int_as_float(b2i); KBLOCK(v2, wd, 32);
    const float v3 = __int_as_float(b3i); KBLOCK(v3, wd, 48);
    return fast_tanh((a0 + a1) + (a2 + a3));
}

// Pre-permuted weight row for the DPP decomposition.
// Received value at (k, r) is h[ ((i&48) | ((i+off(r))&15)) ^ (k<<4) ],
// off(r) = +r or 16-r depending on the probed row_ror direction.
__device__ __forceinline__ void load_wdpp(const float* __restrict__ W, int lane,
                                          bool dirplus, float (&wd)[64]) {
#pragma unroll
    for (int m = 0; m < 64; ++m) {
        const int k = m >> 4, r = m & 15;
        const int lowoff = dirplus ? r : ((16 - r) & 15);
        const int j = ((lane & 48) | ((lane + lowoff) & 15)) ^ (k << 4);
        wd[m] = W[lane * 64 + j];
    }
}

// ---------------------------------------------------------------------------
// prep: pre[s][t][i] = b_ih0[i] + b_hh0[i] + sum_d W_ih0[i][d] * in[0,t,d]
// Only batch element 0 of x / y matters (reference uses e[0], o[0] only).
// ---------------------------------------------------------------------------
__global__ void prep_kernel(const float* __restrict__ x, const float* __restrict__ y,
                            const float* __restrict__ eW, const float* __restrict__ ebi,
                            const float* __restrict__ ebh,
                            const float* __restrict__ oW, const float* __restrict__ obi,
                            const float* __restrict__ obh,
                            float* __restrict__ pre)
{
    int idx = blockIdx.x * blockDim.x + threadIdx.x;   // 2*T*64 threads
    int i = idx & 63;
    int t = (idx >> 6) & (T - 1);
    int s = idx >> 18;
    const float* in = s ? y : x;          // batch 0 = first T*3 floats
    const float* W  = s ? oW : eW;        // [64][3]
    const float* bi = s ? obi : ebi;
    const float* bh = s ? obh : ebh;
    float v = bi[i] + bh[i]
            + W[i*3+0]*in[t*3+0] + W[i*3+1]*in[t*3+1] + W[i*3+2]*in[t*3+2];
    pre[idx] = v;
}

// ---------------------------------------------------------------------------
// seq: grid=2 (one block per RNN), 4 specialized waves, barrier per EP epoch.
// R5 post-mortem: rolled loop regressed (loop/vmcnt overhead in chain);
// reverted to R1's unrolled-epoch structure. R6 replaces the readlane
// broadcast (the measured ~2x hidden-cost class: VALU<->SGPR hazards) with
// the DPP rotation decomposition above.
//   wave0 @ epoch k: h0[t] = tanh(p[t] + Whh0@h0[t-1]), t in [8k, 8k+8)
//   wave1/wave2 @ epoch k: q[t] = b1 + Wih1@h0[t], t-split halves of [8k-8,8k)
//   wave3 @ epoch k: h1[t] = tanh(q[t] + Whh1@h1[t-1]), t in [8k-16, 8k-8)
// Ring safety (mod 32): cross-wave readers >=1 barrier behind writers.
// NOTE: summation ORDER within each dot product changes per lane (rotation
// order vs ascending-j) -> absmax expected small-nonzero (fp32 reassociation
// only; values of h are exact).
// ---------------------------------------------------------------------------
__global__ __launch_bounds__(256, 1) void seq_kernel(
    const float* __restrict__ pre,            // [2][T][64]
    const float* __restrict__ eWhh0, const float* __restrict__ eWih1,
    const float* __restrict__ eWhh1, const float* __restrict__ ebih1,
    const float* __restrict__ ebhh1,
    const float* __restrict__ oWhh0, const float* __restrict__ oWih1,
    const float* __restrict__ oWhh1, const float* __restrict__ obih1,
    const float* __restrict__ obhh1,
    float* __restrict__ hlast)                // [2][64]
{
    const int s    = blockIdx.x;
    const int wv   = threadIdx.x >> 6;
    const int lane = threadIdx.x & 63;

    __shared__ __align__(16) float h0ring[RING][64];
    __shared__ __align__(16) float qring[RING][64];

    const float* p = pre + s * T * 64;

    // Probe the hardware row_ror direction (wave-uniform result).
    const int got = __builtin_amdgcn_update_dpp(0, lane, 0x121, 0xF, 0xF, false);
    const bool dirplus = ((got & 15) == ((lane + 1) & 15));
    // bpermute byte-addresses for the three XOR-copies
    const int a16 = (lane ^ 16) << 2;
    const int a32 = (lane ^ 32) << 2;
    const int a48 = (lane ^ 48) << 2;

    if (wv == 0) {
        // ---------- layer-0 recurrence wave ----------
        const float* Whh0 = s ? oWhh0 : eWhh0;
        float wd[64];
        load_wdpp(Whh0, lane, dirplus, wd);

        float hp = 0.f;                        // h0[t-1]
        float pc[EP], pn[EP];
#pragma unroll
        for (int i = 0; i < EP; ++i) pc[i] = p[i * 64 + lane];

        for (int k = 0; k < NEP; ++k) {
            ANCHOR64(wd);                      // keep weight row resident
            const int base = k * EP;
            // prefetch next epoch's p (consumed next epoch -> latency hidden)
#pragma unroll
            for (int i = 0; i < EP; ++i) {
                int t = base + EP + i;
                pn[i] = (t < T) ? p[t * 64 + lane] : 0.f;
            }
            if (base < T) {                    // wave-uniform scalar branch
#pragma unroll
                for (int i = 0; i < EP; ++i) {
                    hp = rnn_step_dpp(wd, pc[i], hp, a16, a32, a48);
                    h0ring[(base + i) & (RING - 1)][lane] = hp;   // publish
                }
            }
#pragma unroll
            for (int i = 0; i < EP; ++i) pc[i] = pn[i];
            __syncthreads();
        }
    } else if (wv <= 2) {
        // ---------- helper waves: layer-1 input projection, t-split ----------
        const float* Wih1 = s ? oWih1 : eWih1;
        const float  b1   = s ? (obih1[lane] + obhh1[lane])
                              : (ebih1[lane] + ebhh1[lane]);
        float wi[64];
#pragma unroll
        for (int j = 0; j < 64; ++j) wi[j] = Wih1[lane * 64 + j];

        const int i0 = (wv - 1) * (EP / 2);    // wave1: t 0..3, wave2: t 4..7

        for (int k = 0; k < NEP; ++k) {
            ANCHOR64(wi);
            const int base = k * EP - EP;
            if (base >= 0 && base < T) {
#pragma unroll
                for (int i = 0; i < EP / 2; ++i) {
                    const int t = base + i0 + i;
                    const float4* hv = (const float4*)h0ring[t & (RING - 1)];
                    float q[4] = { b1, 0.f, 0.f, 0.f };
#pragma unroll
                    for (int j4 = 0; j4 < 16; ++j4) {
                        float4 u = hv[j4];
                        q[0] = fmaf(wi[4*j4+0], u.x, q[0]);
                        q[1] = fmaf(wi[4*j4+1], u.y, q[1]);
                        q[2] = fmaf(wi[4*j4+2], u.z, q[2]);
                        q[3] = fmaf(wi[4*j4+3], u.w, q[3]);
                    }
                    qring[t & (RING - 1)][lane] = (q[0] + q[1]) + (q[2] + q[3]);
                }
            }
            __syncthreads();
        }
    } else {
        // ---------- layer-1 recurrence wave ----------
        const float* Whh1 = s ? oWhh1 : eWhh1;
        float wd[64];
        load_wdpp(Whh1, lane, dirplus, wd);

        float hp = 0.f;                        // h1[t-1]
        for (int k = 0; k < NEP; ++k) {
            ANCHOR64(wd);
            const int base = k * EP - 2 * EP;
            if (base >= 0) {                   // base+EP-1 <= T-1 by construction
                float qb[EP];
#pragma unroll
                for (int i = 0; i < EP; ++i)   // all written >=1 epoch ago
                    qb[i] = qring[(base + i) & (RING - 1)][lane];
#pragma unroll
                for (int i = 0; i < EP; ++i)
                    hp = rnn_step_dpp(wd, qb[i], hp, a16, a32, a48);
            }
            __syncthreads();
        }
        hlast[s * 64 + lane] = hp;             // h1[T-1]
    }
}

// ---------------------------------------------------------------------------
// head: e0 = fce_w@hx + fce_b ; o0 = fco_w@hy + fco_b ; zz=[e0,o0,z];
//       h = relu(fc1_w@zz + fc1_b) ; out = fc2_w@h + fc2_b
// ---------------------------------------------------------------------------
__global__ void head_kernel(const float* __restrict__ hlast,   // [2][64]
                            const float* __restrict__ z,
                            const float* __restrict__ fce_w, const float* __restrict__ fce_b,
                            const float* __restrict__ fco_w, const float* __restrict__ fco_b,
                            const float* __restrict__ fc1_w, const float* __restrict__ fc1_b,
                            const float* __restrict__ fc2_w, const float* __restrict__ fc2_b,
                            float* __restrict__ out)            // [5]
{
    const int lane = threadIdx.x;   // 64 threads
    __shared__ float zz[9];
    __shared__ float hh[64];

    if (lane < 2) {
        float sacc = fce_b[lane];
        for (int j = 0; j < 64; ++j) sacc += fce_w[lane * 64 + j] * hlast[j];
        zz[lane] = sacc;
    } else if (lane < 4) {
        int r = lane - 2;
        float sacc = fco_b[r];
        for (int j = 0; j < 64; ++j) sacc += fco_w[r * 64 + j] * hlast[64 + j];
        zz[lane] = sacc;
    } else if (lane < 9) {
        zz[lane] = z[lane - 4];
    }
    __syncthreads();

    float sacc = fc1_b[lane];
#pragma unroll
    for (int j = 0; j < 9; ++j) sacc += fc1_w[lane * 9 + j] * zz[j];
    hh[lane] = fmaxf(sacc, 0.f);
    __syncthreads();

    if (lane < 5) {
        float o = fc2_b[lane];
        for (int i = 0; i < 64; ++i) o += fc2_w[lane * 64 + i] * hh[i];
        out[lane] = o;
    }
}

// ---------------------------------------------------------------------------
extern "C" void kernel_launch(void* const* d_in, const int* in_sizes, int n_in,
                              void* d_out, int out_size, void* d_ws, size_t ws_size,
                              hipStream_t stream)
{
    const float* x      = (const float*)d_in[0];
    const float* y      = (const float*)d_in[1];
    const float* z      = (const float*)d_in[2];
    const float* e_Wih0 = (const float*)d_in[3];
    const float* e_Whh0 = (const float*)d_in[4];
    const float* e_bih0 = (const float*)d_in[5];
    const float* e_bhh0 = (const float*)d_in[6];
    const float* e_Wih1 = (const float*)d_in[7];
    const float* e_Whh1 = (const float*)d_in[8];
    const float* e_bih1 = (const float*)d_in[9];
    const float* e_bhh1 = (const float*)d_in[10];
    const float* o_Wih0 = (const float*)d_in[11];
    const float* o_Whh0 = (const float*)d_in[12];
    const float* o_bih0 = (const float*)d_in[13];
    const float* o_bhh0 = (const float*)d_in[14];
    const float* o_Wih1 = (const float*)d_in[15];
    const float* o_Whh1 = (const float*)d_in[16];
    const float* o_bih1 = (const float*)d_in[17];
    const float* o_bhh1 = (const float*)d_in[18];
    const float* fce_w  = (const float*)d_in[19];
    const float* fce_b  = (const float*)d_in[20];
    const float* fco_w  = (const float*)d_in[21];
    const float* fco_b  = (const float*)d_in[22];
    const float* fc1_w  = (const float*)d_in[23];
    const float* fc1_b  = (const float*)d_in[24];
    const float* fc2_w  = (const float*)d_in[25];
    const float* fc2_b  = (const float*)d_in[26];

    float* pre   = (float*)d_ws;            // 2*T*64 floats = 2 MB
    float* hlast = pre + 2 * T * 64;        // 128 floats
    float* out   = (float*)d_out;

    prep_kernel<<<(2 * T * 64) / 256, 256, 0, stream>>>(
        x, y, e_Wih0, e_bih0, e_bhh0, o_Wih0, o_bih0, o_bhh0, pre);

    seq_kernel<<<2, 256, 0, stream>>>(
        pre,
        e_Whh0, e_Wih1, e_Whh1, e_bih1, e_bhh1,
        o_Whh0, o_Wih1, o_Whh1, o_bih1, o_bhh1,
        hlast);

    head_kernel<<<1, 64, 0, stream>>>(
        hlast, z, fce_w, fce_b, fco_w, fco_b, fc1_w, fc1_b, fc2_w, fc2_b, out);
}

// Round 7
// 1095.631 us; speedup vs baseline: 1.8224x; 1.3810x over previous
//
#include <hip/hip_runtime.h>

#define T 4096
#define EP 8                      // steps per barrier epoch
#define RING 32                   // LDS ring depth (disjoint writer/reader mod 32)
#define NEP (T / EP + 2)          // 514 epochs: pipeline depth 2 epochs

// tanh(x) = 1 - 2/(exp(2x)+1). Branch-free, ~1e-6 err.
__device__ __forceinline__ float fast_tanh(float x) {
    float e = __expf(2.0f * x);
    float r = __builtin_amdgcn_rcpf(e + 1.0f);
    return fmaf(-2.0f, r, 1.0f);
}

// 16/64-scalar residency anchors (once per epoch; near-zero cost).
#define ANCHOR16(a, b) asm volatile("" : \
    "+v"((a)[(b)+0]),  "+v"((a)[(b)+1]),  "+v"((a)[(b)+2]),  "+v"((a)[(b)+3]),  \
    "+v"((a)[(b)+4]),  "+v"((a)[(b)+5]),  "+v"((a)[(b)+6]),  "+v"((a)[(b)+7]),  \
    "+v"((a)[(b)+8]),  "+v"((a)[(b)+9]),  "+v"((a)[(b)+10]), "+v"((a)[(b)+11]), \
    "+v"((a)[(b)+12]), "+v"((a)[(b)+13]), "+v"((a)[(b)+14]), "+v"((a)[(b)+15]))
#define ANCHOR64(a) do { ANCHOR16(a, 0); ANCHOR16(a, 16); \
                         ANCHOR16(a, 32); ANCHOR16(a, 48); } while (0)

// ---------------------------------------------------------------------------
// R7: fused single-instruction DPP products.
//   sum_j W[i][j]*h[j] = sum_{k=0..3} sum_{r=0..15} wd[16k+r] * rot_r(h_k)[i]
// h_k[i] = h[i ^ (k<<4)] (3 ds_bpermute XOR-copies + h itself); rot_r = DPP
// row_ror:r. R6 proved the mapping (absmax 0.0) but update_dpp+fmaf did not
// fuse (128 VALU/step). R7 emits v_fmac_f32_dpp directly: 64 insts/step,
// VGPR-only operands, no SGPR/readlane hazards, no LDS latency in the chain.
// DPP HW hazard (VALU write -> DPP read needs 2 wait states; invisible to the
// hazard recognizer inside inline asm) is guarded deterministically: every
// DPP-source register is produced by a {v_mov_b32; s_nop 1} blob, so any DPP
// read of it is >=2 cycles downstream by construction.
// ---------------------------------------------------------------------------
#define ROTF(acc, v, w, R) \
    asm("v_fmac_f32_dpp %0, %1, %2 row_ror:" #R " row_mask:0xf bank_mask:0xf" \
        : "+v"(acc) : "v"(v), "v"(w))

// Hazard-guarded copy: dst is safe as a DPP source for anything sequenced
// after this blob (s_nop 1 = 2 wait states).
#define MOVNOP(dst, src) \
    asm("v_mov_b32 %0, %1\n\ts_nop 1" : "=v"(dst) : "v"(src))

// One 16-rotation block: r=0 plain fma, r=1..15 fused DPP. acc index = r & 3.
#define KBLOCK(v, wd, B) do { \
    a0 = fmaf((v), (wd)[(B) + 0], a0); \
    ROTF(a1, (v), (wd)[(B) + 1],  1);  ROTF(a2, (v), (wd)[(B) + 2],  2); \
    ROTF(a3, (v), (wd)[(B) + 3],  3);  ROTF(a0, (v), (wd)[(B) + 4],  4); \
    ROTF(a1, (v), (wd)[(B) + 5],  5);  ROTF(a2, (v), (wd)[(B) + 6],  6); \
    ROTF(a3, (v), (wd)[(B) + 7],  7);  ROTF(a0, (v), (wd)[(B) + 8],  8); \
    ROTF(a1, (v), (wd)[(B) + 9],  9);  ROTF(a2, (v), (wd)[(B) +10], 10); \
    ROTF(a3, (v), (wd)[(B) +11], 11);  ROTF(a0, (v), (wd)[(B) +12], 12); \
    ROTF(a1, (v), (wd)[(B) +13], 13);  ROTF(a2, (v), (wd)[(B) +14], 14); \
    ROTF(a3, (v), (wd)[(B) +15], 15); \
} while (0)

// One recurrence step. bpermutes issue first (LDS pipe); their ~30-40 cyc
// latency hides under the k=0 block (16 fmac_dpp). Same product terms and
// acc mapping as R6 (absmax 0.0 verified).
__device__ __forceinline__ float rnn_step_dpp(const float (&wd)[64], float init, float hp,
                                              int a16, int a32, int a48) {
    const int hb = __float_as_int(hp);
    const int b1i = __builtin_amdgcn_ds_bpermute(a16, hb);   // h[i^16]
    const int b2i = __builtin_amdgcn_ds_bpermute(a32, hb);   // h[i^32]
    const int b3i = __builtin_amdgcn_ds_bpermute(a48, hb);   // h[i^48]
    float hpD; MOVNOP(hpD, hp);
    float a0 = init, a1 = 0.f, a2 = 0.f, a3 = 0.f;
    KBLOCK(hpD, wd, 0);
    float v1; MOVNOP(v1, __int_as_float(b1i)); KBLOCK(v1, wd, 16);
    float v2; MOVNOP(v2, __int_as_float(b2i)); KBLOCK(v2, wd, 32);
    float v3; MOVNOP(v3, __int_as_float(b3i)); KBLOCK(v3, wd, 48);
    return fast_tanh((a0 + a1) + (a2 + a3));
}

// Pre-permuted weight row for the DPP decomposition (verified R6, absmax 0.0).
// Received value at (k, r) is h[ ((i&48) | ((i+off(r))&15)) ^ (k<<4) ],
// off(r) = +r or 16-r depending on the probed row_ror direction.
__device__ __forceinline__ void load_wdpp(const float* __restrict__ W, int lane,
                                          bool dirplus, float (&wd)[64]) {
#pragma unroll
    for (int m = 0; m < 64; ++m) {
        const int k = m >> 4, r = m & 15;
        const int lowoff = dirplus ? r : ((16 - r) & 15);
        const int j = ((lane & 48) | ((lane + lowoff) & 15)) ^ (k << 4);
        wd[m] = W[lane * 64 + j];
    }
}

// ---------------------------------------------------------------------------
// prep: pre[s][t][i] = b_ih0[i] + b_hh0[i] + sum_d W_ih0[i][d] * in[0,t,d]
// Only batch element 0 of x / y matters (reference uses e[0], o[0] only).
// ---------------------------------------------------------------------------
__global__ void prep_kernel(const float* __restrict__ x, const float* __restrict__ y,
                            const float* __restrict__ eW, const float* __restrict__ ebi,
                            const float* __restrict__ ebh,
                            const float* __restrict__ oW, const float* __restrict__ obi,
                            const float* __restrict__ obh,
                            float* __restrict__ pre)
{
    int idx = blockIdx.x * blockDim.x + threadIdx.x;   // 2*T*64 threads
    int i = idx & 63;
    int t = (idx >> 6) & (T - 1);
    int s = idx >> 18;
    const float* in = s ? y : x;          // batch 0 = first T*3 floats
    const float* W  = s ? oW : eW;        // [64][3]
    const float* bi = s ? obi : ebi;
    const float* bh = s ? obh : ebh;
    float v = bi[i] + bh[i]
            + W[i*3+0]*in[t*3+0] + W[i*3+1]*in[t*3+1] + W[i*3+2]*in[t*3+2];
    pre[idx] = v;
}

// ---------------------------------------------------------------------------
// seq: grid=2 (one block per RNN), 4 specialized waves, barrier per EP epoch.
//   wave0 @ epoch k: h0[t] = tanh(p[t] + Whh0@h0[t-1]), t in [8k, 8k+8)
//   wave1/wave2 @ epoch k: q[t] = b1 + Wih1@h0[t], t-split halves of [8k-8,8k)
//   wave3 @ epoch k: h1[t] = tanh(q[t] + Whh1@h1[t-1]), t in [8k-16, 8k-8)
// Ring safety (mod 32): cross-wave readers >=1 barrier behind writers.
// ---------------------------------------------------------------------------
__global__ __launch_bounds__(256, 1) void seq_kernel(
    const float* __restrict__ pre,            // [2][T][64]
    const float* __restrict__ eWhh0, const float* __restrict__ eWih1,
    const float* __restrict__ eWhh1, const float* __restrict__ ebih1,
    const float* __restrict__ ebhh1,
    const float* __restrict__ oWhh0, const float* __restrict__ oWih1,
    const float* __restrict__ oWhh1, const float* __restrict__ obih1,
    const float* __restrict__ obhh1,
    float* __restrict__ hlast)                // [2][64]
{
    const int s    = blockIdx.x;
    const int wv   = threadIdx.x >> 6;
    const int lane = threadIdx.x & 63;

    __shared__ __align__(16) float h0ring[RING][64];
    __shared__ __align__(16) float qring[RING][64];

    const float* p = pre + s * T * 64;

    // Probe the hardware row_ror direction (wave-uniform result).
    const int got = __builtin_amdgcn_update_dpp(0, lane, 0x121, 0xF, 0xF, false);
    const bool dirplus = ((got & 15) == ((lane + 1) & 15));
    // bpermute byte-addresses for the three XOR-copies
    const int a16 = (lane ^ 16) << 2;
    const int a32 = (lane ^ 32) << 2;
    const int a48 = (lane ^ 48) << 2;

    if (wv == 0) {
        // ---------- layer-0 recurrence wave ----------
        const float* Whh0 = s ? oWhh0 : eWhh0;
        float wd[64];
        load_wdpp(Whh0, lane, dirplus, wd);

        float hp = 0.f;                        // h0[t-1]
        float pc[EP], pn[EP];
#pragma unroll
        for (int i = 0; i < EP; ++i) pc[i] = p[i * 64 + lane];

        for (int k = 0; k < NEP; ++k) {
            ANCHOR64(wd);                      // keep weight row resident
            const int base = k * EP;
            // prefetch next epoch's p (consumed next epoch -> latency hidden)
#pragma unroll
            for (int i = 0; i < EP; ++i) {
                int t = base + EP + i;
                pn[i] = (t < T) ? p[t * 64 + lane] : 0.f;
            }
            if (base < T) {                    // wave-uniform scalar branch
#pragma unroll
                for (int i = 0; i < EP; ++i) {
                    hp = rnn_step_dpp(wd, pc[i], hp, a16, a32, a48);
                    h0ring[(base + i) & (RING - 1)][lane] = hp;   // publish
                }
            }
#pragma unroll
            for (int i = 0; i < EP; ++i) pc[i] = pn[i];
            __syncthreads();
        }
    } else if (wv <= 2) {
        // ---------- helper waves: layer-1 input projection, t-split ----------
        const float* Wih1 = s ? oWih1 : eWih1;
        const float  b1   = s ? (obih1[lane] + obhh1[lane])
                              : (ebih1[lane] + ebhh1[lane]);
        float wi[64];
#pragma unroll
        for (int j = 0; j < 64; ++j) wi[j] = Wih1[lane * 64 + j];

        const int i0 = (wv - 1) * (EP / 2);    // wave1: t 0..3, wave2: t 4..7

        for (int k = 0; k < NEP; ++k) {
            ANCHOR64(wi);
            const int base = k * EP - EP;
            if (base >= 0 && base < T) {
#pragma unroll
                for (int i = 0; i < EP / 2; ++i) {
                    const int t = base + i0 + i;
                    const float4* hv = (const float4*)h0ring[t & (RING - 1)];
                    float q[4] = { b1, 0.f, 0.f, 0.f };
#pragma unroll
                    for (int j4 = 0; j4 < 16; ++j4) {
                        float4 u = hv[j4];
                        q[0] = fmaf(wi[4*j4+0], u.x, q[0]);
                        q[1] = fmaf(wi[4*j4+1], u.y, q[1]);
                        q[2] = fmaf(wi[4*j4+2], u.z, q[2]);
                        q[3] = fmaf(wi[4*j4+3], u.w, q[3]);
                    }
                    qring[t & (RING - 1)][lane] = (q[0] + q[1]) + (q[2] + q[3]);
                }
            }
            __syncthreads();
        }
    } else {
        // ---------- layer-1 recurrence wave ----------
        const float* Whh1 = s ? oWhh1 : eWhh1;
        float wd[64];
        load_wdpp(Whh1, lane, dirplus, wd);

        float hp = 0.f;                        // h1[t-1]
        for (int k = 0; k < NEP; ++k) {
            ANCHOR64(wd);
            const int base = k * EP - 2 * EP;
            if (base >= 0) {                   // base+EP-1 <= T-1 by construction
                float qb[EP];
#pragma unroll
                for (int i = 0; i < EP; ++i)   // all written >=1 epoch ago
                    qb[i] = qring[(base + i) & (RING - 1)][lane];
#pragma unroll
                for (int i = 0; i < EP; ++i)
                    hp = rnn_step_dpp(wd, qb[i], hp, a16, a32, a48);
            }
            __syncthreads();
        }
        hlast[s * 64 + lane] = hp;             // h1[T-1]
    }
}

// ---------------------------------------------------------------------------
// head: e0 = fce_w@hx + fce_b ; o0 = fco_w@hy + fco_b ; zz=[e0,o0,z];
//       h = relu(fc1_w@zz + fc1_b) ; out = fc2_w@h + fc2_b
// ---------------------------------------------------------------------------
__global__ void head_kernel(const float* __restrict__ hlast,   // [2][64]
                            const float* __restrict__ z,
                            const float* __restrict__ fce_w, const float* __restrict__ fce_b,
                            const float* __restrict__ fco_w, const float* __restrict__ fco_b,
                            const float* __restrict__ fc1_w, const float* __restrict__ fc1_b,
                            const float* __restrict__ fc2_w, const float* __restrict__ fc2_b,
                            float* __restrict__ out)            // [5]
{
    const int lane = threadIdx.x;   // 64 threads
    __shared__ float zz[9];
    __shared__ float hh[64];

    if (lane < 2) {
        float sacc = fce_b[lane];
        for (int j = 0; j < 64; ++j) sacc += fce_w[lane * 64 + j] * hlast[j];
        zz[lane] = sacc;
    } else if (lane < 4) {
        int r = lane - 2;
        float sacc = fco_b[r];
        for (int j = 0; j < 64; ++j) sacc += fco_w[r * 64 + j] * hlast[64 + j];
        zz[lane] = sacc;
    } else if (lane < 9) {
        zz[lane] = z[lane - 4];
    }
    __syncthreads();

    float sacc = fc1_b[lane];
#pragma unroll
    for (int j = 0; j < 9; ++j) sacc += fc1_w[lane * 9 + j] * zz[j];
    hh[lane] = fmaxf(sacc, 0.f);
    __syncthreads();

    if (lane < 5) {
        float o = fc2_b[lane];
        for (int i = 0; i < 64; ++i) o += fc2_w[lane * 64 + i] * hh[i];
        out[lane] = o;
    }
}

// ---------------------------------------------------------------------------
extern "C" void kernel_launch(void* const* d_in, const int* in_sizes, int n_in,
                              void* d_out, int out_size, void* d_ws, size_t ws_size,
                              hipStream_t stream)
{
    const float* x      = (const float*)d_in[0];
    const float* y      = (const float*)d_in[1];
    const float* z      = (const float*)d_in[2];
    const float* e_Wih0 = (const float*)d_in[3];
    const float* e_Whh0 = (const float*)d_in[4];
    const float* e_bih0 = (const float*)d_in[5];
    const float* e_bhh0 = (const float*)d_in[6];
    const float* e_Wih1 = (const float*)d_in[7];
    const float* e_Whh1 = (const float*)d_in[8];
    const float* e_bih1 = (const float*)d_in[9];
    const float* e_bhh1 = (const float*)d_in[10];
    const float* o_Wih0 = (const float*)d_in[11];
    const float* o_Whh0 = (const float*)d_in[12];
    const float* o_bih0 = (const float*)d_in[13];
    const float* o_bhh0 = (const float*)d_in[14];
    const float* o_Wih1 = (const float*)d_in[15];
    const float* o_Whh1 = (const float*)d_in[16];
    const float* o_bih1 = (const float*)d_in[17];
    const float* o_bhh1 = (const float*)d_in[18];
    const float* fce_w  = (const float*)d_in[19];
    const float* fce_b  = (const float*)d_in[20];
    const float* fco_w  = (const float*)d_in[21];
    const float* fco_b  = (const float*)d_in[22];
    const float* fc1_w  = (const float*)d_in[23];
    const float* fc1_b  = (const float*)d_in[24];
    const float* fc2_w  = (const float*)d_in[25];
    const float* fc2_b  = (const float*)d_in[26];

    float* pre   = (float*)d_ws;            // 2*T*64 floats = 2 MB
    float* hlast = pre + 2 * T * 64;        // 128 floats
    float* out   = (float*)d_out;

    prep_kernel<<<(2 * T * 64) / 256, 256, 0, stream>>>(
        x, y, e_Wih0, e_bih0, e_bhh0, o_Wih0, o_bih0, o_bhh0, pre);

    seq_kernel<<<2, 256, 0, stream>>>(
        pre,
        e_Whh0, e_Wih1, e_Whh1, e_bih1, e_bhh1,
        o_Whh0, o_Wih1, o_Whh1, o_bih1, o_bhh1,
        hlast);

    head_kernel<<<1, 64, 0, stream>>>(
        hlast, z, fce_w, fce_b, fco_w, fco_b, fc1_w, fc1_b, fc2_w, fc2_b, out);
}